// Round 6
// baseline (238.708 us; speedup 1.0000x reference)
//
#include <hip/hip_runtime.h>

typedef __bf16 bf16x8 __attribute__((ext_vector_type(8)));
typedef __bf16 bf16x4 __attribute__((ext_vector_type(4)));
typedef float f32x4 __attribute__((ext_vector_type(4)));

namespace {
constexpr int Bn = 2, Cn = 64, hn = 96, wn = 96, Hn = 384, Wn = 384;
constexpr int CIN = 266;
constexpr int TM = 64;                      // pixels per workgroup tile
constexpr int SP = 296;                     // Abuf row stride (bf16): 592B
// fragment-major weight layouts. A-frag mapping for mfma_f32_16x16x32_bf16:
// lane l supplies A[m = l&15][k = (l>>4)*8 + j].
constexpr int L1_FRAGS = 9 * 16 * 64;       // 9216
constexpr int L2_FRAGS = 8 * 16 * 64;       // 8192
constexpr int L3_FRAGS = 8 * 64;            // 512
constexpr int N_FRAGS = L1_FRAGS + L2_FRAGS + L3_FRAGS;   // 17920
constexpr int SC_OFF_BYTES = N_FRAGS * 16;                 // 286720
constexpr int B1EFF_OFF_BYTES = SC_OFF_BYTES + Bn * 3 * hn * wn * 4;
constexpr int FRAG_BLOCKS = N_FRAGS / 256;  // 70
constexpr int NPIX = Bn * hn * wn;          // 18432
constexpr int SC_BLOCKS = NPIX / 64;        // 288 (4 threads per pixel)
}

// ---------------- prep (single dispatch): weight frags + b1eff + shortcut MLP ----------------
__global__ void prep_all(const float* __restrict__ w00, const float* __restrict__ w1,
                         const float* __restrict__ w2, const float* __restrict__ b00,
                         const float* __restrict__ b1,
                         const float* __restrict__ feat, const float* __restrict__ ws1,
                         const float* __restrict__ bs1, const float* __restrict__ ws2,
                         const float* __restrict__ bs2,
                         __bf16* __restrict__ wb, float* __restrict__ b1eff,
                         float* __restrict__ sc)
{
    const int bid = blockIdx.x;
    if (bid < FRAG_BLOCKS) {
        const int f = bid * 256 + threadIdx.x;
        bf16x8 v;
        if (f < L1_FRAGS) {
            const int k0 = f >> 10;
            const int mb = (f >> 6) & 15;
            const int l  = f & 63;
            const int m  = mb * 16 + (l & 15);
            const int kb = k0 * 32 + (l >> 4) * 8;
#pragma unroll
            for (int j = 0; j < 8; j++)
                v[j] = (kb + j < CIN) ? (__bf16)w00[m * CIN + kb + j] : (__bf16)0.f;
        } else if (f < L1_FRAGS + L2_FRAGS) {
            const int g = f - L1_FRAGS;
            const int k0 = g >> 10;
            const int mb = (g >> 6) & 15;
            const int l  = g & 63;
            const int m  = mb * 16 + (l & 15);
            const int kb = k0 * 32 + (l >> 4) * 8;
#pragma unroll
            for (int j = 0; j < 8; j++) v[j] = (__bf16)w1[m * 256 + kb + j];
        } else {
            const int g = f - (L1_FRAGS + L2_FRAGS);
            const int k0 = g >> 6;
            const int l  = g & 63;
            const int m  = l & 15;
            const int kb = k0 * 32 + (l >> 4) * 8;
#pragma unroll
            for (int j = 0; j < 8; j++)
                v[j] = (m < 3) ? (__bf16)w2[m * 256 + kb + j] : (__bf16)0.f;
        }
        *(bf16x8*)(wb + f * 8) = v;
        return;
    }
    if (bid == FRAG_BLOCKS) {
        // b1eff[o] = b1[o] + sum_c w1[o][c]*(b00[c] + 0.5*(w00[c][264]+w00[c][265]))
        __shared__ float cb[256];
        const int o = threadIdx.x;
        cb[o] = b00[o] + 0.5f * (w00[o * CIN + 264] + w00[o * CIN + 265]);
        __syncthreads();
        float v = b1[o];
#pragma unroll 4
        for (int k = 0; k < 256; k++) v = fmaf(w1[o * 256 + k], cb[k], v);
        b1eff[o] = v;
        return;
    }
    // shortcut MLP: 4 threads per pixel, each handles 16 of the 64 hidden chans
    const int pix = (bid - FRAG_BLOCKS - 1) * 64 + (threadIdx.x >> 2);
    const int part = threadIdx.x & 3;
    if (pix >= NPIX) return;
    const int b = pix / (hn * wn);
    const int yx = pix % (hn * wn);
    const float* fp = feat + b * Cn * hn * wn + yx;
    float f[Cn];
#pragma unroll
    for (int c = 0; c < Cn; c++) f[c] = fp[c * hn * wn];
    float o0 = 0.f, o1 = 0.f, o2 = 0.f;
    const int co0 = part * 16;
#pragma unroll 1
    for (int u = 0; u < 16; u += 4) {
        const int co = co0 + u;
        float v0 = bs1[co], v1 = bs1[co + 1], v2 = bs1[co + 2], v3 = bs1[co + 3];
        const float* wr = ws1 + co * Cn;
#pragma unroll
        for (int ci = 0; ci < Cn; ci++) {
            const float fv = f[ci];
            v0 = fmaf(wr[ci], fv, v0);
            v1 = fmaf(wr[Cn + ci], fv, v1);
            v2 = fmaf(wr[2 * Cn + ci], fv, v2);
            v3 = fmaf(wr[3 * Cn + ci], fv, v3);
        }
        v0 = fmaxf(v0, 0.f); v1 = fmaxf(v1, 0.f); v2 = fmaxf(v2, 0.f); v3 = fmaxf(v3, 0.f);
#pragma unroll
        for (int q = 0; q < 4; q++) {
            const float vv = (q == 0) ? v0 : (q == 1) ? v1 : (q == 2) ? v2 : v3;
            o0 = fmaf(ws2[co + q], vv, o0);
            o1 = fmaf(ws2[Cn + co + q], vv, o1);
            o2 = fmaf(ws2[2 * Cn + co + q], vv, o2);
        }
    }
    // reduce across the 4 parts (adjacent lanes)
    o0 += __shfl_xor(o0, 1); o0 += __shfl_xor(o0, 2);
    o1 += __shfl_xor(o1, 1); o1 += __shfl_xor(o1, 2);
    o2 += __shfl_xor(o2, 1); o2 += __shfl_xor(o2, 2);
    if (part == 0) {
        sc[(b * 3 + 0) * hn * wn + yx] = o0 + bs2[0];
        sc[(b * 3 + 1) * hn * wn + yx] = o1 + bs2[1];
        sc[(b * 3 + 2) * hn * wn + yx] = o2 + bs2[2];
    }
}

__device__ __forceinline__ float gelu_fast(float x) {
    // tanh-form gelu via sigmoid in exp2 domain: x * 1/(1 + 2^(x*(d0+d1*x^2)))
    const float d0 = -2.302118074f;   // -2*0.7978845608*log2(e)
    const float d1 = -0.1029453754f;  // -2*0.0356774081*log2(e)
    float t = x * x;
    float a = x * fmaf(t, d1, d0);
    float e = __builtin_amdgcn_exp2f(a);
    return x * __builtin_amdgcn_rcpf(1.f + e);
}

__device__ __forceinline__ bf16x4 pack4(f32x4 x) {
    bf16x4 v;
    v[0] = (__bf16)x[0]; v[1] = (__bf16)x[1]; v[2] = (__bf16)x[2]; v[3] = (__bf16)x[3];
    return v;
}

// ---------------- fused main kernel ----------------
// Operand-swapped GEMMs: D = W (A-operand, global->VGPR stream) x Act^T
// (B-operand from LDS). Hot-loop state is fully scalarized (R3/R4 lesson:
// array/lambda indirection -> failed mem2reg -> scratch spill -> 40-60MB HBM
// traffic). R6 change: SINGLE-buffer distance-1 weight prefetch (wA0..3,
// 16 regs instead of 32) to get total unified regs <= 128 -> 4 waves/SIMD
// (16 waves/CU). With 4 waves sharing the matrix pipe, a kstep's 16-MFMA
// burst stretches ~4x, fully covering the L2 latency of the dist-1 loads.

#define MF(A, B, C) __builtin_amdgcn_mfma_f32_16x16x32_bf16((A), (B), (C), 0, 0, 0)

// 16 MFMAs of one kstep: weights W0..W3 (mblocks mb0..mb0+3) x 4 pixel-blocks
#define GSTEP(k0) do {                                                          \
    const bf16x8 g0 = *(const bf16x8*)&Abuf[     lane16][(k0) * 32 + quad * 8]; \
    const bf16x8 g1 = *(const bf16x8*)&Abuf[16 + lane16][(k0) * 32 + quad * 8]; \
    const bf16x8 g2 = *(const bf16x8*)&Abuf[32 + lane16][(k0) * 32 + quad * 8]; \
    const bf16x8 g3 = *(const bf16x8*)&Abuf[48 + lane16][(k0) * 32 + quad * 8]; \
    a00 = MF(wA0, g0, a00); a01 = MF(wA1, g0, a01); a02 = MF(wA2, g0, a02); a03 = MF(wA3, g0, a03); \
    a10 = MF(wA0, g1, a10); a11 = MF(wA1, g1, a11); a12 = MF(wA2, g1, a12); a13 = MF(wA3, g1, a13); \
    a20 = MF(wA0, g2, a20); a21 = MF(wA1, g2, a21); a22 = MF(wA2, g2, a22); a23 = MF(wA3, g2, a23); \
    a30 = MF(wA0, g3, a30); a31 = MF(wA1, g3, a31); a32 = MF(wA2, g3, a32); a33 = MF(wA3, g3, a33); \
} while (0)

#define LDW(src, kk) do {                               \
    wA0 = (src)[((kk) * 16 + mb0 + 0) * 64 + lane];     \
    wA1 = (src)[((kk) * 16 + mb0 + 1) * 64 + lane];     \
    wA2 = (src)[((kk) * 16 + mb0 + 2) * 64 + lane];     \
    wA3 = (src)[((kk) * 16 + mb0 + 3) * 64 + lane];     \
} while (0)

#define ZACC4(n) a##n##0 = zf; a##n##1 = zf; a##n##2 = zf; a##n##3 = zf

__global__ __launch_bounds__(256, 4) void liif_main(
    const float* __restrict__ feat, const float* __restrict__ b1eff,
    const float* __restrict__ b2v, const __bf16* __restrict__ wb,
    const float* __restrict__ sc, float* __restrict__ out)
{
    __shared__ __align__(16) __bf16 Abuf[TM][SP];

    const int t = threadIdx.x;
    const int wv = t >> 6;
    const int lane = t & 63;
    const int lane16 = lane & 15;
    const int quad = lane >> 4;
    const int mb0 = wv * 4;

    // XCD swizzle: HW assigns XCD = blockIdx % 8; remap so each XCD owns a
    // contiguous Y-band (614 KB feat slice stays L2-resident). FETCH 26->4MB.
    constexpr int NWG = Bn * Hn * (Wn / TM);       // 4608
    const int lt = (blockIdx.x & 7) * (NWG / 8) + (blockIdx.x >> 3);
    constexpr int TPR = Wn / TM;  // 6 tiles per HR row
    const int tx = lt % TPR;
    const int Y = (lt / TPR) % Hn;
    const int b = lt / (TPR * Hn);
    const int X0 = tx * TM;

    const float cy = -1.f + 1.f / Hn + (2.f / Hn) * (float)Y;

    const bf16x8* wf1 = (const bf16x8*)wb;
    const bf16x8* wf2 = wf1 + L1_FRAGS;
    const bf16x8* w2f = wf1 + (L1_FRAGS + L2_FRAGS);

    // layer-1 kstep0 prefetch issued BEFORE the gather
    bf16x8 wA0, wA1, wA2, wA3;
    LDW(wf1, 0);

    // ---------- phase 1: build grid features [64 x 266] bf16 in Abuf ----------
    {
        const int p = lane;     // pixel in tile
        const int j = wv;       // this wave handles corner j's gather
        const int X = X0 + p;
        const float cx = -1.f + 1.f / Wn + (2.f / Wn) * (float)X;
        float rely[4], relx[4], area[4];
        int iyv[4], ixv[4];
#pragma unroll
        for (int c = 0; c < 4; c++) {
            const float vx = (c & 2) ? 1.f : -1.f;   // shift along height
            const float vy = (c & 1) ? 1.f : -1.f;   // shift along width
            float sy = fminf(fmaxf(cy + vx * (1.f / hn) + 1e-6f, -1.f + 1e-6f), 1.f - 1e-6f);
            float sx = fminf(fmaxf(cx + vy * (1.f / wn) + 1e-6f, -1.f + 1e-6f), 1.f - 1e-6f);
            float uy = ((sy + 1.f) * hn - 1.f) * 0.5f;
            float ux = ((sx + 1.f) * wn - 1.f) * 0.5f;
            int iy = min(max((int)rintf(uy), 0), hn - 1);   // round-half-even == jnp.round
            int ix = min(max((int)rintf(ux), 0), wn - 1);
            float oy = -1.f + 1.f / hn + (2.f / hn) * (float)iy;
            float ox = -1.f + 1.f / wn + (2.f / wn) * (float)ix;
            rely[c] = (cy - oy) * hn;
            relx[c] = (cx - ox) * wn;
            area[c] = fabsf(rely[c] * relx[c]) + 1e-9f;
            iyv[c] = iy; ixv[c] = ix;
        }
        const float tot = area[0] + area[1] + area[2] + area[3];
        const float wj = area[3 - j] / tot;   // LIIF area swap 0<->3, 1<->2

        if (j == 0) {  // channels 0..7: [rel_y0, rel_x0, ..., rel_y3, rel_x3]
            bf16x8 v;
#pragma unroll
            for (int c = 0; c < 4; c++) { v[2 * c] = (__bf16)rely[c]; v[2 * c + 1] = (__bf16)relx[c]; }
            *(bf16x8*)&Abuf[p][0] = v;
        }
        // channels 8+64j .. 8+64j+63: feat at (iy_j, ix_j) scaled by wj
        const float* fb = feat + ((b * Cn) * hn + iyv[j]) * wn + ixv[j];
#pragma unroll
        for (int c8 = 0; c8 < 8; c8++) {
            bf16x8 v;
#pragma unroll
            for (int cc = 0; cc < 8; cc++)
                v[cc] = (__bf16)(fb[(c8 * 8 + cc) * (hn * wn)] * wj);
            *(bf16x8*)&Abuf[p][8 + 64 * j + c8 * 8] = v;
        }
        if (j == 3) {  // channels 264..287 zero (rel_cell folded into b1eff)
            bf16x8 z;
#pragma unroll
            for (int cc = 0; cc < 8; cc++) z[cc] = (__bf16)0.f;
            *(bf16x8*)&Abuf[p][264] = z;
            *(bf16x8*)&Abuf[p][272] = z;
            *(bf16x8*)&Abuf[p][280] = z;
        }
    }
    __syncthreads();

    const f32x4 zf = (f32x4){0.f, 0.f, 0.f, 0.f};
    f32x4 a00, a01, a02, a03, a10, a11, a12, a13;
    f32x4 a20, a21, a22, a23, a30, a31, a32, a33;
    ZACC4(0); ZACC4(1); ZACC4(2); ZACC4(3);

    // ---------- layer 1: W00[256x288] x G^T, 9 ksteps (dist-1 prefetch) ----------
    GSTEP(0); LDW(wf1, 1);
    GSTEP(1); LDW(wf1, 2);
    GSTEP(2); LDW(wf1, 3);
    GSTEP(3); LDW(wf1, 4);
    GSTEP(4); LDW(wf1, 5);
    GSTEP(5); LDW(wf1, 6);
    GSTEP(6); LDW(wf1, 7);
    GSTEP(7); LDW(wf1, 8);
    GSTEP(8); LDW(wf2, 0);   // next layer kstep0

    __syncthreads();  // all grid readers done before overwriting Abuf with X
    // epilogue 1: no bias (b00 + rel_cell folded into b1eff); packed b64 writes
    {
        const int ch0 = mb0 * 16 + quad * 4;
        *(bf16x4*)&Abuf[     lane16][ch0     ] = pack4(a00);
        *(bf16x4*)&Abuf[16 + lane16][ch0     ] = pack4(a10);
        *(bf16x4*)&Abuf[32 + lane16][ch0     ] = pack4(a20);
        *(bf16x4*)&Abuf[48 + lane16][ch0     ] = pack4(a30);
        *(bf16x4*)&Abuf[     lane16][ch0 + 16] = pack4(a01);
        *(bf16x4*)&Abuf[16 + lane16][ch0 + 16] = pack4(a11);
        *(bf16x4*)&Abuf[32 + lane16][ch0 + 16] = pack4(a21);
        *(bf16x4*)&Abuf[48 + lane16][ch0 + 16] = pack4(a31);
        *(bf16x4*)&Abuf[     lane16][ch0 + 32] = pack4(a02);
        *(bf16x4*)&Abuf[16 + lane16][ch0 + 32] = pack4(a12);
        *(bf16x4*)&Abuf[32 + lane16][ch0 + 32] = pack4(a22);
        *(bf16x4*)&Abuf[48 + lane16][ch0 + 32] = pack4(a32);
        *(bf16x4*)&Abuf[     lane16][ch0 + 48] = pack4(a03);
        *(bf16x4*)&Abuf[16 + lane16][ch0 + 48] = pack4(a13);
        *(bf16x4*)&Abuf[32 + lane16][ch0 + 48] = pack4(a23);
        *(bf16x4*)&Abuf[48 + lane16][ch0 + 48] = pack4(a33);
    }
    __syncthreads();

    ZACC4(0); ZACC4(1); ZACC4(2); ZACC4(3);

    // ---------- layer 2: W1[256x256] x X, 8 ksteps ----------
    GSTEP(0); LDW(wf2, 1);
    GSTEP(1); LDW(wf2, 2);
    GSTEP(2); LDW(wf2, 3);
    GSTEP(3); LDW(wf2, 4);
    GSTEP(4); LDW(wf2, 5);
    GSTEP(5); LDW(wf2, 6);
    GSTEP(6); LDW(wf2, 7);
    GSTEP(7); wA0 = w2f[0 * 64 + lane]; wA1 = w2f[1 * 64 + lane];  // w2 k0,k1

    __syncthreads();
    // epilogue 2: bias + gelu, packed b64 writes
    {
        const int ch0 = mb0 * 16 + quad * 4;
        const f32x4 bi0 = *(const f32x4*)&b1eff[ch0];
        const f32x4 bi1 = *(const f32x4*)&b1eff[ch0 + 16];
        const f32x4 bi2 = *(const f32x4*)&b1eff[ch0 + 32];
        const f32x4 bi3 = *(const f32x4*)&b1eff[ch0 + 48];
#define GEL4(x, bi) { bf16x4 v; v[0] = (__bf16)gelu_fast((x)[0] + (bi)[0]); \
        v[1] = (__bf16)gelu_fast((x)[1] + (bi)[1]); \
        v[2] = (__bf16)gelu_fast((x)[2] + (bi)[2]); \
        v[3] = (__bf16)gelu_fast((x)[3] + (bi)[3]); vv = v; }
        bf16x4 vv;
        GEL4(a00, bi0); *(bf16x4*)&Abuf[     lane16][ch0     ] = vv;
        GEL4(a10, bi0); *(bf16x4*)&Abuf[16 + lane16][ch0     ] = vv;
        GEL4(a20, bi0); *(bf16x4*)&Abuf[32 + lane16][ch0     ] = vv;
        GEL4(a30, bi0); *(bf16x4*)&Abuf[48 + lane16][ch0     ] = vv;
        GEL4(a01, bi1); *(bf16x4*)&Abuf[     lane16][ch0 + 16] = vv;
        GEL4(a11, bi1); *(bf16x4*)&Abuf[16 + lane16][ch0 + 16] = vv;
        GEL4(a21, bi1); *(bf16x4*)&Abuf[32 + lane16][ch0 + 16] = vv;
        GEL4(a31, bi1); *(bf16x4*)&Abuf[48 + lane16][ch0 + 16] = vv;
        GEL4(a02, bi2); *(bf16x4*)&Abuf[     lane16][ch0 + 32] = vv;
        GEL4(a12, bi2); *(bf16x4*)&Abuf[16 + lane16][ch0 + 32] = vv;
        GEL4(a22, bi2); *(bf16x4*)&Abuf[32 + lane16][ch0 + 32] = vv;
        GEL4(a32, bi2); *(bf16x4*)&Abuf[48 + lane16][ch0 + 32] = vv;
        GEL4(a03, bi3); *(bf16x4*)&Abuf[     lane16][ch0 + 48] = vv;
        GEL4(a13, bi3); *(bf16x4*)&Abuf[16 + lane16][ch0 + 48] = vv;
        GEL4(a23, bi3); *(bf16x4*)&Abuf[32 + lane16][ch0 + 48] = vv;
        GEL4(a33, bi3); *(bf16x4*)&Abuf[48 + lane16][ch0 + 48] = vv;
#undef GEL4
    }
    __syncthreads();

    // ---------- layer 3: W2[16x256] x Y, 8 ksteps; wave wv owns pixel-block wv ----------
    f32x4 acc3 = zf;
#define YF(k0) (*(const bf16x8*)&Abuf[wv * 16 + lane16][(k0) * 32 + quad * 8])
    acc3 = MF(wA0, YF(0), acc3); wA0 = w2f[2 * 64 + lane];
    acc3 = MF(wA1, YF(1), acc3); wA1 = w2f[3 * 64 + lane];
    acc3 = MF(wA0, YF(2), acc3); wA0 = w2f[4 * 64 + lane];
    acc3 = MF(wA1, YF(3), acc3); wA1 = w2f[5 * 64 + lane];
    acc3 = MF(wA0, YF(4), acc3); wA0 = w2f[6 * 64 + lane];
    acc3 = MF(wA1, YF(5), acc3); wA1 = w2f[7 * 64 + lane];
    acc3 = MF(wA0, YF(6), acc3);
    acc3 = MF(wA1, YF(7), acc3);
#undef YF

    // ---------- epilogue: rows 0..2 (quad 0) hold the 3 output channels ----------
    if (quad == 0) {
        const int pix = wv * 16 + lane16;
        const int X = X0 + pix;
        const float uy = ((cy + 1.f) * hn - 1.f) * 0.5f;
        const float fy = floorf(uy);
        const float wy = uy - fy;
        const int y0i = min(max((int)fy, 0), hn - 1);
        const int y1i = min(max((int)fy + 1, 0), hn - 1);
        const float cx = -1.f + 1.f / Wn + (2.f / Wn) * (float)X;
        const float ux = ((cx + 1.f) * wn - 1.f) * 0.5f;
        const float fx = floorf(ux);
        const float wx = ux - fx;
        const int x0i = min(max((int)fx, 0), wn - 1);
        const int x1i = min(max((int)fx + 1, 0), wn - 1);
        const float w00b = (1.f - wy) * (1.f - wx), w01b = (1.f - wy) * wx;
        const float w10b = wy * (1.f - wx), w11b = wy * wx;
#pragma unroll
        for (int r = 0; r < 3; r++) {
            const float* scb = sc + (b * 3 + r) * (hn * wn);
            const float samp = scb[y0i * wn + x0i] * w00b + scb[y0i * wn + x1i] * w01b
                             + scb[y1i * wn + x0i] * w10b + scb[y1i * wn + x1i] * w11b;
            out[((b * 3 + r) * Hn + Y) * Wn + X] = acc3[r] + b2v[r] + samp;
        }
    }
}

extern "C" void kernel_launch(void* const* d_in, const int* in_sizes, int n_in,
                              void* d_out, int out_size, void* d_ws, size_t ws_size,
                              hipStream_t stream)
{
    const float* feat = (const float*)d_in[0];
    const float* w00  = (const float*)d_in[1];
    const float* b00  = (const float*)d_in[2];
    const float* w1   = (const float*)d_in[3];
    const float* b1   = (const float*)d_in[4];
    const float* w2   = (const float*)d_in[5];
    const float* b2   = (const float*)d_in[6];
    const float* ws1  = (const float*)d_in[7];
    const float* bs1  = (const float*)d_in[8];
    const float* ws2  = (const float*)d_in[9];
    const float* bs2  = (const float*)d_in[10];
    float* out = (float*)d_out;

    __bf16* wb    = (__bf16*)d_ws;
    float* scbuf  = (float*)((char*)d_ws + SC_OFF_BYTES);
    float* b1eff  = (float*)((char*)d_ws + B1EFF_OFF_BYTES);

    prep_all<<<FRAG_BLOCKS + 1 + SC_BLOCKS, 256, 0, stream>>>(
        w00, w1, w2, b00, b1, feat, ws1, bs1, ws2, bs2, wb, b1eff, scbuf);
    liif_main<<<Bn * Hn * (Wn / TM), 256, 0, stream>>>(feat, b1eff, b2, wb, scbuf, out);
}

// Round 7
// 209.582 us; speedup vs baseline: 1.1390x; 1.1390x over previous
//
#include <hip/hip_runtime.h>

typedef __bf16 bf16x8 __attribute__((ext_vector_type(8)));
typedef __bf16 bf16x4 __attribute__((ext_vector_type(4)));
typedef float f32x4 __attribute__((ext_vector_type(4)));

namespace {
constexpr int Bn = 2, Cn = 64, hn = 96, wn = 96, Hn = 384, Wn = 384;
constexpr int CIN = 266;
constexpr int TM = 64;                      // pixels per workgroup tile
constexpr int SP = 296;                     // Abuf row stride (bf16): 592B
// fragment-major weight layouts. A-frag mapping for mfma_f32_16x16x32_bf16:
// lane l supplies A[m = l&15][k = (l>>4)*8 + j].
constexpr int L1_FRAGS = 9 * 16 * 64;       // 9216
constexpr int L2_FRAGS = 8 * 16 * 64;       // 8192
constexpr int L3_FRAGS = 8 * 64;            // 512
constexpr int N_FRAGS = L1_FRAGS + L2_FRAGS + L3_FRAGS;   // 17920
constexpr int SC_OFF_BYTES = N_FRAGS * 16;                 // 286720
constexpr int B1EFF_OFF_BYTES = SC_OFF_BYTES + Bn * 3 * hn * wn * 4;
constexpr int FRAG_BLOCKS = N_FRAGS / 256;  // 70
constexpr int NPIX = Bn * hn * wn;          // 18432
constexpr int SC_BLOCKS = NPIX / 256;       // 72 (1 thread per pixel — R5 proven)
}

// ---------------- prep (single dispatch): weight frags + b1eff + shortcut MLP ----------------
__global__ void prep_all(const float* __restrict__ w00, const float* __restrict__ w1,
                         const float* __restrict__ w2, const float* __restrict__ b00,
                         const float* __restrict__ b1,
                         const float* __restrict__ feat, const float* __restrict__ ws1,
                         const float* __restrict__ bs1, const float* __restrict__ ws2,
                         const float* __restrict__ bs2,
                         __bf16* __restrict__ wb, float* __restrict__ b1eff,
                         float* __restrict__ sc)
{
    const int bid = blockIdx.x;
    if (bid < FRAG_BLOCKS) {
        const int f = bid * 256 + threadIdx.x;
        bf16x8 v;
        if (f < L1_FRAGS) {
            const int k0 = f >> 10;
            const int mb = (f >> 6) & 15;
            const int l  = f & 63;
            const int m  = mb * 16 + (l & 15);
            const int kb = k0 * 32 + (l >> 4) * 8;
#pragma unroll
            for (int j = 0; j < 8; j++)
                v[j] = (kb + j < CIN) ? (__bf16)w00[m * CIN + kb + j] : (__bf16)0.f;
        } else if (f < L1_FRAGS + L2_FRAGS) {
            const int g = f - L1_FRAGS;
            const int k0 = g >> 10;
            const int mb = (g >> 6) & 15;
            const int l  = g & 63;
            const int m  = mb * 16 + (l & 15);
            const int kb = k0 * 32 + (l >> 4) * 8;
#pragma unroll
            for (int j = 0; j < 8; j++) v[j] = (__bf16)w1[m * 256 + kb + j];
        } else {
            const int g = f - (L1_FRAGS + L2_FRAGS);
            const int k0 = g >> 6;
            const int l  = g & 63;
            const int m  = l & 15;
            const int kb = k0 * 32 + (l >> 4) * 8;
#pragma unroll
            for (int j = 0; j < 8; j++)
                v[j] = (m < 3) ? (__bf16)w2[m * 256 + kb + j] : (__bf16)0.f;
        }
        *(bf16x8*)(wb + f * 8) = v;
        return;
    }
    if (bid == FRAG_BLOCKS) {
        // b1eff[o] = b1[o] + sum_c w1[o][c]*(b00[c] + 0.5*(w00[c][264]+w00[c][265]))
        __shared__ float cb[256];
        const int o = threadIdx.x;
        cb[o] = b00[o] + 0.5f * (w00[o * CIN + 264] + w00[o * CIN + 265]);
        __syncthreads();
        float v = b1[o];
#pragma unroll 4
        for (int k = 0; k < 256; k++) v = fmaf(w1[o * 256 + k], cb[k], v);
        b1eff[o] = v;
        return;
    }
    // shortcut MLP on LR grid (1 thread per pixel — R5 proven form)
    const int t = (bid - FRAG_BLOCKS - 1) * 256 + threadIdx.x;
    if (t >= NPIX) return;
    const int b = t / (hn * wn);
    const int yx = t % (hn * wn);
    const float* fp = feat + b * Cn * hn * wn + yx;
    float f[Cn];
#pragma unroll
    for (int c = 0; c < Cn; c++) f[c] = fp[c * hn * wn];
    float o0 = bs2[0], o1 = bs2[1], o2 = bs2[2];
#pragma unroll 1
    for (int co = 0; co < Cn; co += 4) {
        float v0 = bs1[co], v1 = bs1[co + 1], v2 = bs1[co + 2], v3 = bs1[co + 3];
        const float* wr = ws1 + co * Cn;
#pragma unroll
        for (int ci = 0; ci < Cn; ci++) {
            const float fv = f[ci];
            v0 = fmaf(wr[ci], fv, v0);
            v1 = fmaf(wr[Cn + ci], fv, v1);
            v2 = fmaf(wr[2 * Cn + ci], fv, v2);
            v3 = fmaf(wr[3 * Cn + ci], fv, v3);
        }
        v0 = fmaxf(v0, 0.f); v1 = fmaxf(v1, 0.f); v2 = fmaxf(v2, 0.f); v3 = fmaxf(v3, 0.f);
#pragma unroll
        for (int u = 0; u < 4; u++) {
            const float vv = (u == 0) ? v0 : (u == 1) ? v1 : (u == 2) ? v2 : v3;
            o0 = fmaf(ws2[co + u], vv, o0);
            o1 = fmaf(ws2[Cn + co + u], vv, o1);
            o2 = fmaf(ws2[2 * Cn + co + u], vv, o2);
        }
    }
    sc[(b * 3 + 0) * hn * wn + yx] = o0;
    sc[(b * 3 + 1) * hn * wn + yx] = o1;
    sc[(b * 3 + 2) * hn * wn + yx] = o2;
}

__device__ __forceinline__ float gelu_fast(float x) {
    // tanh-form gelu via sigmoid in exp2 domain: x * 1/(1 + 2^(x*(d0+d1*x^2)))
    const float d0 = -2.302118074f;   // -2*0.7978845608*log2(e)
    const float d1 = -0.1029453754f;  // -2*0.0356774081*log2(e)
    float t = x * x;
    float a = x * fmaf(t, d1, d0);
    float e = __builtin_amdgcn_exp2f(a);
    return x * __builtin_amdgcn_rcpf(1.f + e);
}

__device__ __forceinline__ bf16x4 pack4(f32x4 x) {
    bf16x4 v;
    v[0] = (__bf16)x[0]; v[1] = (__bf16)x[1]; v[2] = (__bf16)x[2]; v[3] = (__bf16)x[3];
    return v;
}

// ---------------- fused main kernel (512 threads = 8 waves) ----------------
// Operand-swapped GEMMs: D = W (A-operand, global->VGPR stream) x Act^T
// (B-operand from LDS). Scalarized hot state (R3/R4 lesson: arrays/lambdas
// on the buffer -> failed mem2reg -> scratch spill). R6 lesson: 64 acc regs
// + 4 waves/SIMD cap (128) = guaranteed spill. So R7: 8 waves/WG, each wave
// owns 2 m-blocks x 4 pixel-blocks = 32 acc regs; live set ~95 regs fits the
// 128 cap -> 16 waves/CU WITHOUT spill, and per-WG weight traffic unchanged
// (8 waves cover 16 m-blocks exactly once; L2 stays ~13 TB/s).

#define MF(A, B, C) __builtin_amdgcn_mfma_f32_16x16x32_bf16((A), (B), (C), 0, 0, 0)

// 8 MFMAs of one kstep: weights W0,W1 (mblocks mb0,mb0+1) x 4 pixel-blocks
#define GSTEP(k0, W0, W1) do {                                                  \
    const bf16x8 g0 = *(const bf16x8*)&Abuf[     lane16][(k0) * 32 + quad * 8]; \
    const bf16x8 g1 = *(const bf16x8*)&Abuf[16 + lane16][(k0) * 32 + quad * 8]; \
    const bf16x8 g2 = *(const bf16x8*)&Abuf[32 + lane16][(k0) * 32 + quad * 8]; \
    const bf16x8 g3 = *(const bf16x8*)&Abuf[48 + lane16][(k0) * 32 + quad * 8]; \
    a00 = MF(W0, g0, a00); a01 = MF(W1, g0, a01);                               \
    a10 = MF(W0, g1, a10); a11 = MF(W1, g1, a11);                               \
    a20 = MF(W0, g2, a20); a21 = MF(W1, g2, a21);                               \
    a30 = MF(W0, g3, a30); a31 = MF(W1, g3, a31);                               \
} while (0)

#define LDW(W0, W1, src, kk) do {                       \
    W0 = (src)[((kk) * 16 + mb0 + 0) * 64 + lane];      \
    W1 = (src)[((kk) * 16 + mb0 + 1) * 64 + lane];      \
} while (0)

__global__ __launch_bounds__(512, 4) void liif_main(
    const float* __restrict__ feat, const float* __restrict__ b1eff,
    const float* __restrict__ b2v, const __bf16* __restrict__ wb,
    const float* __restrict__ sc, float* __restrict__ out)
{
    __shared__ __align__(16) __bf16 Abuf[TM][SP];

    const int t = threadIdx.x;
    const int wv = t >> 6;        // 0..7
    const int lane = t & 63;
    const int lane16 = lane & 15;
    const int quad = lane >> 4;
    const int mb0 = wv * 2;       // 2 m-blocks per wave

    // XCD swizzle: HW assigns XCD = blockIdx % 8; remap so each XCD owns a
    // contiguous Y-band (614 KB feat slice stays L2-resident).
    constexpr int NWG = Bn * Hn * (Wn / TM);       // 4608
    const int lt = (blockIdx.x & 7) * (NWG / 8) + (blockIdx.x >> 3);
    constexpr int TPR = Wn / TM;  // 6 tiles per HR row
    const int tx = lt % TPR;
    const int Y = (lt / TPR) % Hn;
    const int b = lt / (TPR * Hn);
    const int X0 = tx * TM;

    const float cy = -1.f + 1.f / Hn + (2.f / Hn) * (float)Y;

    const bf16x8* wf1 = (const bf16x8*)wb;
    const bf16x8* wf2 = wf1 + L1_FRAGS;
    const bf16x8* w2f = wf1 + (L1_FRAGS + L2_FRAGS);

    // ---------- phase 1: build grid features [64 x 266] bf16 in Abuf ----------
    // corner j = wv&3; half = wv>>2 selects channels 0-31 / 32-63 of that corner.
    {
        const int p = lane;           // pixel in tile
        const int j = wv & 3;
        const int half = wv >> 2;
        const int X = X0 + p;
        const float cx = -1.f + 1.f / Wn + (2.f / Wn) * (float)X;
        float rely[4], relx[4], area[4];
        int iyv[4], ixv[4];
#pragma unroll
        for (int c = 0; c < 4; c++) {
            const float vx = (c & 2) ? 1.f : -1.f;   // shift along height
            const float vy = (c & 1) ? 1.f : -1.f;   // shift along width
            float sy = fminf(fmaxf(cy + vx * (1.f / hn) + 1e-6f, -1.f + 1e-6f), 1.f - 1e-6f);
            float sx = fminf(fmaxf(cx + vy * (1.f / wn) + 1e-6f, -1.f + 1e-6f), 1.f - 1e-6f);
            float uy = ((sy + 1.f) * hn - 1.f) * 0.5f;
            float ux = ((sx + 1.f) * wn - 1.f) * 0.5f;
            int iy = min(max((int)rintf(uy), 0), hn - 1);   // round-half-even == jnp.round
            int ix = min(max((int)rintf(ux), 0), wn - 1);
            float oy = -1.f + 1.f / hn + (2.f / hn) * (float)iy;
            float ox = -1.f + 1.f / wn + (2.f / wn) * (float)ix;
            rely[c] = (cy - oy) * hn;
            relx[c] = (cx - ox) * wn;
            area[c] = fabsf(rely[c] * relx[c]) + 1e-9f;
            iyv[c] = iy; ixv[c] = ix;
        }
        const float tot = area[0] + area[1] + area[2] + area[3];
        const float wj = area[3 - j] / tot;   // LIIF area swap 0<->3, 1<->2

        if (wv == 0) {  // channels 0..7: [rel_y0, rel_x0, ..., rel_y3, rel_x3]
            bf16x8 v;
#pragma unroll
            for (int c = 0; c < 4; c++) { v[2 * c] = (__bf16)rely[c]; v[2 * c + 1] = (__bf16)relx[c]; }
            *(bf16x8*)&Abuf[p][0] = v;
        }
        // channels 8+64j+32*half .. +31: feat at (iy_j, ix_j) scaled by wj
        const float* fb = feat + ((b * Cn + half * 32) * hn + iyv[j]) * wn + ixv[j];
#pragma unroll
        for (int c8 = 0; c8 < 4; c8++) {
            bf16x8 v;
#pragma unroll
            for (int cc = 0; cc < 8; cc++)
                v[cc] = (__bf16)(fb[(c8 * 8 + cc) * (hn * wn)] * wj);
            *(bf16x8*)&Abuf[p][8 + 64 * j + half * 32 + c8 * 8] = v;
        }
        if (wv == 3) {  // channels 264..287 zero (rel_cell folded into b1eff)
            bf16x8 z;
#pragma unroll
            for (int cc = 0; cc < 8; cc++) z[cc] = (__bf16)0.f;
            *(bf16x8*)&Abuf[p][264] = z;
            *(bf16x8*)&Abuf[p][272] = z;
            *(bf16x8*)&Abuf[p][280] = z;
        }
    }

    // layer-1 initial prefetch (ksteps 0,1) AFTER gather (low reg pressure there)
    bf16x8 wE0, wE1, wO0, wO1;
    LDW(wE0, wE1, wf1, 0);
    LDW(wO0, wO1, wf1, 1);
    __syncthreads();

    const f32x4 zf = (f32x4){0.f, 0.f, 0.f, 0.f};
    f32x4 a00, a01, a10, a11, a20, a21, a30, a31;
    a00 = zf; a01 = zf; a10 = zf; a11 = zf; a20 = zf; a21 = zf; a30 = zf; a31 = zf;

    // ---------- layer 1: W00[256x288] x G^T, 9 ksteps ----------
    GSTEP(0, wE0, wE1); LDW(wE0, wE1, wf1, 2);
    GSTEP(1, wO0, wO1); LDW(wO0, wO1, wf1, 3);
    GSTEP(2, wE0, wE1); LDW(wE0, wE1, wf1, 4);
    GSTEP(3, wO0, wO1); LDW(wO0, wO1, wf1, 5);
    GSTEP(4, wE0, wE1); LDW(wE0, wE1, wf1, 6);
    GSTEP(5, wO0, wO1); LDW(wO0, wO1, wf1, 7);
    GSTEP(6, wE0, wE1); LDW(wE0, wE1, wf1, 8);
    GSTEP(7, wO0, wO1); LDW(wO0, wO1, wf2, 0);  // next layer k0
    GSTEP(8, wE0, wE1); LDW(wE0, wE1, wf2, 1);  // next layer k1

    __syncthreads();  // all grid readers done before overwriting Abuf with X
    // epilogue 1: no bias (b00 + rel_cell folded into b1eff); packed b64 writes
    {
        const int ch0 = mb0 * 16 + quad * 4;
        *(bf16x4*)&Abuf[     lane16][ch0     ] = pack4(a00);
        *(bf16x4*)&Abuf[16 + lane16][ch0     ] = pack4(a10);
        *(bf16x4*)&Abuf[32 + lane16][ch0     ] = pack4(a20);
        *(bf16x4*)&Abuf[48 + lane16][ch0     ] = pack4(a30);
        *(bf16x4*)&Abuf[     lane16][ch0 + 16] = pack4(a01);
        *(bf16x4*)&Abuf[16 + lane16][ch0 + 16] = pack4(a11);
        *(bf16x4*)&Abuf[32 + lane16][ch0 + 16] = pack4(a21);
        *(bf16x4*)&Abuf[48 + lane16][ch0 + 16] = pack4(a31);
    }
    __syncthreads();

    a00 = zf; a01 = zf; a10 = zf; a11 = zf; a20 = zf; a21 = zf; a30 = zf; a31 = zf;

    // ---------- layer 2: W1[256x256] x X, 8 ksteps (k0 in wO, k1 in wE) ----------
    GSTEP(0, wO0, wO1); LDW(wO0, wO1, wf2, 2);
    GSTEP(1, wE0, wE1); LDW(wE0, wE1, wf2, 3);
    GSTEP(2, wO0, wO1); LDW(wO0, wO1, wf2, 4);
    GSTEP(3, wE0, wE1); LDW(wE0, wE1, wf2, 5);
    GSTEP(4, wO0, wO1); LDW(wO0, wO1, wf2, 6);
    GSTEP(5, wE0, wE1); LDW(wE0, wE1, wf2, 7);
    GSTEP(6, wO0, wO1); wO0 = w2f[0 * 64 + lane];          // w2 k0
    GSTEP(7, wE0, wE1); wE0 = w2f[1 * 64 + lane];          // w2 k1

    __syncthreads();
    // epilogue 2: bias + gelu, packed b64 writes
    {
        const int ch0 = mb0 * 16 + quad * 4;
        const f32x4 bi0 = *(const f32x4*)&b1eff[ch0];
        const f32x4 bi1 = *(const f32x4*)&b1eff[ch0 + 16];
#define GEL4(x, bi) { bf16x4 v; v[0] = (__bf16)gelu_fast((x)[0] + (bi)[0]); \
        v[1] = (__bf16)gelu_fast((x)[1] + (bi)[1]); \
        v[2] = (__bf16)gelu_fast((x)[2] + (bi)[2]); \
        v[3] = (__bf16)gelu_fast((x)[3] + (bi)[3]); vv = v; }
        bf16x4 vv;
        GEL4(a00, bi0); *(bf16x4*)&Abuf[     lane16][ch0     ] = vv;
        GEL4(a10, bi0); *(bf16x4*)&Abuf[16 + lane16][ch0     ] = vv;
        GEL4(a20, bi0); *(bf16x4*)&Abuf[32 + lane16][ch0     ] = vv;
        GEL4(a30, bi0); *(bf16x4*)&Abuf[48 + lane16][ch0     ] = vv;
        GEL4(a01, bi1); *(bf16x4*)&Abuf[     lane16][ch0 + 16] = vv;
        GEL4(a11, bi1); *(bf16x4*)&Abuf[16 + lane16][ch0 + 16] = vv;
        GEL4(a21, bi1); *(bf16x4*)&Abuf[32 + lane16][ch0 + 16] = vv;
        GEL4(a31, bi1); *(bf16x4*)&Abuf[48 + lane16][ch0 + 16] = vv;
#undef GEL4
    }
    __syncthreads();

    // ---------- layer 3: W2[16x256] x Y, 8 ksteps; waves 0-3 own pixel-blocks ----------
    if (wv < 4) {
        f32x4 acc3 = zf;
#define YF(k0) (*(const bf16x8*)&Abuf[wv * 16 + lane16][(k0) * 32 + quad * 8])
        acc3 = MF(wO0, YF(0), acc3); wO0 = w2f[2 * 64 + lane];
        acc3 = MF(wE0, YF(1), acc3); wE0 = w2f[3 * 64 + lane];
        acc3 = MF(wO0, YF(2), acc3); wO0 = w2f[4 * 64 + lane];
        acc3 = MF(wE0, YF(3), acc3); wE0 = w2f[5 * 64 + lane];
        acc3 = MF(wO0, YF(4), acc3); wO0 = w2f[6 * 64 + lane];
        acc3 = MF(wE0, YF(5), acc3); wE0 = w2f[7 * 64 + lane];
        acc3 = MF(wO0, YF(6), acc3);
        acc3 = MF(wE0, YF(7), acc3);
#undef YF

        // ---------- epilogue: rows 0..2 (quad 0) hold the 3 output channels ----------
        if (quad == 0) {
            const int pix = wv * 16 + lane16;
            const int X = X0 + pix;
            const float uy = ((cy + 1.f) * hn - 1.f) * 0.5f;
            const float fy = floorf(uy);
            const float wy = uy - fy;
            const int y0i = min(max((int)fy, 0), hn - 1);
            const int y1i = min(max((int)fy + 1, 0), hn - 1);
            const float cx = -1.f + 1.f / Wn + (2.f / Wn) * (float)X;
            const float ux = ((cx + 1.f) * wn - 1.f) * 0.5f;
            const float fx = floorf(ux);
            const float wx = ux - fx;
            const int x0i = min(max((int)fx, 0), wn - 1);
            const int x1i = min(max((int)fx + 1, 0), wn - 1);
            const float w00b = (1.f - wy) * (1.f - wx), w01b = (1.f - wy) * wx;
            const float w10b = wy * (1.f - wx), w11b = wy * wx;
#pragma unroll
            for (int r = 0; r < 3; r++) {
                const float* scb = sc + (b * 3 + r) * (hn * wn);
                const float samp = scb[y0i * wn + x0i] * w00b + scb[y0i * wn + x1i] * w01b
                                 + scb[y1i * wn + x0i] * w10b + scb[y1i * wn + x1i] * w11b;
                out[((b * 3 + r) * Hn + Y) * Wn + X] = acc3[r] + b2v[r] + samp;
            }
        }
    }
}

extern "C" void kernel_launch(void* const* d_in, const int* in_sizes, int n_in,
                              void* d_out, int out_size, void* d_ws, size_t ws_size,
                              hipStream_t stream)
{
    const float* feat = (const float*)d_in[0];
    const float* w00  = (const float*)d_in[1];
    const float* b00  = (const float*)d_in[2];
    const float* w1   = (const float*)d_in[3];
    const float* b1   = (const float*)d_in[4];
    const float* w2   = (const float*)d_in[5];
    const float* b2   = (const float*)d_in[6];
    const float* ws1  = (const float*)d_in[7];
    const float* bs1  = (const float*)d_in[8];
    const float* ws2  = (const float*)d_in[9];
    const float* bs2  = (const float*)d_in[10];
    float* out = (float*)d_out;

    __bf16* wb    = (__bf16*)d_ws;
    float* scbuf  = (float*)((char*)d_ws + SC_OFF_BYTES);
    float* b1eff  = (float*)((char*)d_ws + B1EFF_OFF_BYTES);

    prep_all<<<FRAG_BLOCKS + 1 + SC_BLOCKS, 256, 0, stream>>>(
        w00, w1, w2, b00, b1, feat, ws1, bs1, ws2, bs2, wb, b1eff, scbuf);
    liif_main<<<Bn * Hn * (Wn / TM), 512, 0, stream>>>(feat, b1eff, b2, wb, scbuf, out);
}

// Round 8
// 208.574 us; speedup vs baseline: 1.1445x; 1.0048x over previous
//
#include <hip/hip_runtime.h>

typedef __bf16 bf16x8 __attribute__((ext_vector_type(8)));
typedef __bf16 bf16x4 __attribute__((ext_vector_type(4)));
typedef float f32x4 __attribute__((ext_vector_type(4)));
typedef float f32x16 __attribute__((ext_vector_type(16)));

namespace {
constexpr int Bn = 2, Cn = 64, hn = 96, wn = 96, Hn = 384, Wn = 384;
constexpr int CIN = 266;
constexpr int TM = 64;                      // pixels per workgroup tile
constexpr int SP = 296;                     // Abuf row stride (bf16): 592B, 37 16B-blocks
// Weight frag layouts (built by prep_all):
//  L1/L2: 32x32x16 A-frags: lane l supplies A[m = ob*32 + (l&31)][k = k0*16 + (l>>5)*8 + j]
//         stored at [(k0*8 + ob)*64 + l], ob in [0,8)
//  L3:    16x16x32 A-frags: lane l supplies A[m = l&15][k = k0*32 + (l>>4)*8 + j]
constexpr int L1_FRAGS = 18 * 8 * 64;       // 9216  (K=288 -> 18 ksteps of 16)
constexpr int L2_FRAGS = 16 * 8 * 64;       // 8192  (K=256)
constexpr int L3_FRAGS = 8 * 64;            // 512
constexpr int N_FRAGS = L1_FRAGS + L2_FRAGS + L3_FRAGS;   // 17920
constexpr int SC_OFF_BYTES = N_FRAGS * 16;                 // 286720
constexpr int B1EFF_OFF_BYTES = SC_OFF_BYTES + Bn * 3 * hn * wn * 4;
constexpr int FRAG_BLOCKS = N_FRAGS / 256;  // 70
constexpr int NPIX = Bn * hn * wn;          // 18432
constexpr int SC_BLOCKS = NPIX / 256;       // 72
}

// ---------------- prep (single dispatch): weight frags + b1eff + shortcut MLP ----------------
__global__ void prep_all(const float* __restrict__ w00, const float* __restrict__ w1,
                         const float* __restrict__ w2, const float* __restrict__ b00,
                         const float* __restrict__ b1,
                         const float* __restrict__ feat, const float* __restrict__ ws1,
                         const float* __restrict__ bs1, const float* __restrict__ ws2,
                         const float* __restrict__ bs2,
                         __bf16* __restrict__ wb, float* __restrict__ b1eff,
                         float* __restrict__ sc)
{
    const int bid = blockIdx.x;
    if (bid < FRAG_BLOCKS) {
        const int f = bid * 256 + threadIdx.x;
        bf16x8 v;
        if (f < L1_FRAGS) {                 // 32x32x16 A layout
            const int k0 = f >> 9;          // 512 frags per kstep (8 ob x 64 lanes)
            const int ob = (f >> 6) & 7;
            const int l  = f & 63;
            const int m  = ob * 32 + (l & 31);
            const int kb = k0 * 16 + (l >> 5) * 8;
#pragma unroll
            for (int j = 0; j < 8; j++)
                v[j] = (kb + j < CIN) ? (__bf16)w00[m * CIN + kb + j] : (__bf16)0.f;
        } else if (f < L1_FRAGS + L2_FRAGS) {
            const int g = f - L1_FRAGS;
            const int k0 = g >> 9;
            const int ob = (g >> 6) & 7;
            const int l  = g & 63;
            const int m  = ob * 32 + (l & 31);
            const int kb = k0 * 16 + (l >> 5) * 8;
#pragma unroll
            for (int j = 0; j < 8; j++) v[j] = (__bf16)w1[m * 256 + kb + j];
        } else {                            // L3: 16x16x32 A layout (unchanged)
            const int g = f - (L1_FRAGS + L2_FRAGS);
            const int k0 = g >> 6;
            const int l  = g & 63;
            const int m  = l & 15;
            const int kb = k0 * 32 + (l >> 4) * 8;
#pragma unroll
            for (int j = 0; j < 8; j++)
                v[j] = (m < 3) ? (__bf16)w2[m * 256 + kb + j] : (__bf16)0.f;
        }
        *(bf16x8*)(wb + f * 8) = v;
        return;
    }
    if (bid == FRAG_BLOCKS) {
        // b1eff[o] = b1[o] + sum_c w1[o][c]*(b00[c] + 0.5*(w00[c][264]+w00[c][265]))
        __shared__ float cb[256];
        const int o = threadIdx.x;
        cb[o] = b00[o] + 0.5f * (w00[o * CIN + 264] + w00[o * CIN + 265]);
        __syncthreads();
        float v = b1[o];
#pragma unroll 4
        for (int k = 0; k < 256; k++) v = fmaf(w1[o * 256 + k], cb[k], v);
        b1eff[o] = v;
        return;
    }
    // shortcut MLP on LR grid (1 thread per pixel — R5 proven form)
    const int t = (bid - FRAG_BLOCKS - 1) * 256 + threadIdx.x;
    if (t >= NPIX) return;
    const int b = t / (hn * wn);
    const int yx = t % (hn * wn);
    const float* fp = feat + b * Cn * hn * wn + yx;
    float f[Cn];
#pragma unroll
    for (int c = 0; c < Cn; c++) f[c] = fp[c * hn * wn];
    float o0 = bs2[0], o1 = bs2[1], o2 = bs2[2];
#pragma unroll 1
    for (int co = 0; co < Cn; co += 4) {
        float v0 = bs1[co], v1 = bs1[co + 1], v2 = bs1[co + 2], v3 = bs1[co + 3];
        const float* wr = ws1 + co * Cn;
#pragma unroll
        for (int ci = 0; ci < Cn; ci++) {
            const float fv = f[ci];
            v0 = fmaf(wr[ci], fv, v0);
            v1 = fmaf(wr[Cn + ci], fv, v1);
            v2 = fmaf(wr[2 * Cn + ci], fv, v2);
            v3 = fmaf(wr[3 * Cn + ci], fv, v3);
        }
        v0 = fmaxf(v0, 0.f); v1 = fmaxf(v1, 0.f); v2 = fmaxf(v2, 0.f); v3 = fmaxf(v3, 0.f);
#pragma unroll
        for (int u = 0; u < 4; u++) {
            const float vv = (u == 0) ? v0 : (u == 1) ? v1 : (u == 2) ? v2 : v3;
            o0 = fmaf(ws2[co + u], vv, o0);
            o1 = fmaf(ws2[Cn + co + u], vv, o1);
            o2 = fmaf(ws2[2 * Cn + co + u], vv, o2);
        }
    }
    sc[(b * 3 + 0) * hn * wn + yx] = o0;
    sc[(b * 3 + 1) * hn * wn + yx] = o1;
    sc[(b * 3 + 2) * hn * wn + yx] = o2;
}

__device__ __forceinline__ float gelu_fast(float x) {
    // tanh-form gelu via sigmoid in exp2 domain: x * 1/(1 + 2^(x*(d0+d1*x^2)))
    const float d0 = -2.302118074f;   // -2*0.7978845608*log2(e)
    const float d1 = -0.1029453754f;  // -2*0.0356774081*log2(e)
    float t = x * x;
    float a = x * fmaf(t, d1, d0);
    float e = __builtin_amdgcn_exp2f(a);
    return x * __builtin_amdgcn_rcpf(1.f + e);
}

__device__ __forceinline__ bf16x4 pk4(float a, float b, float c, float d) {
    bf16x4 v; v[0] = (__bf16)a; v[1] = (__bf16)b; v[2] = (__bf16)c; v[3] = (__bf16)d;
    return v;
}

// ---------------- fused main kernel (R5 skeleton + 32x32x16 MFMA + LDS swizzle) ------------
// Operand-swapped GEMMs: D = W (A-operand, global->VGPR 4-phase dist-4 stream)
// x Act^T (B-operand from LDS). Scalarized hot state (R3/R4: arrays/lambdas
// -> scratch spill). R6/R7: occupancy pushes lose; keep 256thr/3WG-CU shape.
// LDS 16B-block XOR swizzle: phys_blk = blk ^ ((row>>3)&3). Makes the 32-row
// b128 B-frag reads conflict-free (stride-148dw rows alias banks with period
// 8; xor separates rows r, r+8, r+16, r+24 into disjoint 4-bank windows).

#define MF32(A, B, C) __builtin_amdgcn_mfma_f32_32x32x16_bf16((A), (B), (C), 0, 0, 0)
#define MF16(A, B, C) __builtin_amdgcn_mfma_f32_16x16x32_bf16((A), (B), (C), 0, 0, 0)

// one kstep (K=16): weights W0,W1 (out-blocks ob0,ob0+1) x 2 px-blocks
#define GS(k0, W0, W1) do {                                                     \
    const int pc = (((2 * (k0) + hi) ^ skey) * 8);                              \
    const bf16x8 g0 = *(const bf16x8*)&Abuf[     lane31][pc];                   \
    const bf16x8 g1 = *(const bf16x8*)&Abuf[32 + lane31][pc];                   \
    c00 = MF32(W0, g0, c00); c01 = MF32(W1, g0, c01);                           \
    c10 = MF32(W0, g1, c10); c11 = MF32(W1, g1, c11);                           \
} while (0)

#define LW(W0, W1, src, kk) do {                        \
    W0 = (src)[((kk) * 8 + ob0 + 0) * 64 + lane];       \
    W1 = (src)[((kk) * 8 + ob0 + 1) * 64 + lane];       \
} while (0)

// epilogue-1 store of one f32x16 tile (out-block OB, row ROW=px)
#define EP1(ACC, OB, ROW) do {                                                          \
    *(bf16x4*)&Abuf[ROW][(((OB) * 4 + 0) ^ skey) * 8 + hi * 4] = pk4((ACC)[0], (ACC)[1], (ACC)[2], (ACC)[3]);     \
    *(bf16x4*)&Abuf[ROW][(((OB) * 4 + 1) ^ skey) * 8 + hi * 4] = pk4((ACC)[4], (ACC)[5], (ACC)[6], (ACC)[7]);     \
    *(bf16x4*)&Abuf[ROW][(((OB) * 4 + 2) ^ skey) * 8 + hi * 4] = pk4((ACC)[8], (ACC)[9], (ACC)[10], (ACC)[11]);   \
    *(bf16x4*)&Abuf[ROW][(((OB) * 4 + 3) ^ skey) * 8 + hi * 4] = pk4((ACC)[12], (ACC)[13], (ACC)[14], (ACC)[15]); \
} while (0)

// epilogue-2: bias + gelu for px-block pair (A0 row lane31, A1 row 32+lane31)
#define EP2G(A0, A1, OB, G) do {                                                        \
    const f32x4 bi = *(const f32x4*)&b1eff[(OB) * 32 + 8 * (G) + hi * 4];               \
    *(bf16x4*)&Abuf[     lane31][(((OB) * 4 + (G)) ^ skey) * 8 + hi * 4] =              \
        pk4(gelu_fast((A0)[4*(G)+0] + bi[0]), gelu_fast((A0)[4*(G)+1] + bi[1]),         \
            gelu_fast((A0)[4*(G)+2] + bi[2]), gelu_fast((A0)[4*(G)+3] + bi[3]));        \
    *(bf16x4*)&Abuf[32 + lane31][(((OB) * 4 + (G)) ^ skey) * 8 + hi * 4] =              \
        pk4(gelu_fast((A1)[4*(G)+0] + bi[0]), gelu_fast((A1)[4*(G)+1] + bi[1]),         \
            gelu_fast((A1)[4*(G)+2] + bi[2]), gelu_fast((A1)[4*(G)+3] + bi[3]));        \
} while (0)

__global__ __launch_bounds__(256, 3) void liif_main(
    const float* __restrict__ feat, const float* __restrict__ b1eff,
    const float* __restrict__ b2v, const __bf16* __restrict__ wb,
    const float* __restrict__ sc, float* __restrict__ out)
{
    __shared__ __align__(16) __bf16 Abuf[TM][SP];

    const int t = threadIdx.x;
    const int wv = t >> 6;        // 0..3
    const int lane = t & 63;
    const int lane31 = lane & 31;
    const int hi = lane >> 5;     // 0/1: k-half within 32x32x16 frag
    const int skey = (lane31 >> 3) & 3;   // LDS swizzle key for rows lane31 / 32+lane31
    const int lane16 = lane & 15;
    const int quad = lane >> 4;
    const int ob0 = wv * 2;       // 2 out-blocks (of 32) per wave

    // XCD swizzle: HW assigns XCD = blockIdx % 8; remap so each XCD owns a
    // contiguous Y-band (614 KB feat slice stays L2-resident).
    constexpr int NWG = Bn * Hn * (Wn / TM);       // 4608
    const int lt = (blockIdx.x & 7) * (NWG / 8) + (blockIdx.x >> 3);
    constexpr int TPR = Wn / TM;  // 6 tiles per HR row
    const int tx = lt % TPR;
    const int Y = (lt / TPR) % Hn;
    const int b = lt / (TPR * Hn);
    const int X0 = tx * TM;

    const float cy = -1.f + 1.f / Hn + (2.f / Hn) * (float)Y;

    const bf16x8* wf1 = (const bf16x8*)wb;
    const bf16x8* wf2 = wf1 + L1_FRAGS;
    const bf16x8* w2f = wf1 + (L1_FRAGS + L2_FRAGS);

    // 4-phase dist-4 weight pipeline; initial loads issued BEFORE the gather
    bf16x8 wP00, wP01, wP10, wP11, wP20, wP21, wP30, wP31;
    LW(wP00, wP01, wf1, 0);
    LW(wP10, wP11, wf1, 1);
    LW(wP20, wP21, wf1, 2);
    LW(wP30, wP31, wf1, 3);

    // ---------- phase 1: build grid features [64 x 266] bf16 in Abuf (swizzled) ----------
    {
        const int p = lane;     // pixel in tile
        const int j = wv;       // this wave handles corner j's gather
        const int pkey = (p >> 3) & 3;
        const int X = X0 + p;
        const float cx = -1.f + 1.f / Wn + (2.f / Wn) * (float)X;
        float rely[4], relx[4], area[4];
        int iyv[4], ixv[4];
#pragma unroll
        for (int c = 0; c < 4; c++) {
            const float vx = (c & 2) ? 1.f : -1.f;   // shift along height
            const float vy = (c & 1) ? 1.f : -1.f;   // shift along width
            float sy = fminf(fmaxf(cy + vx * (1.f / hn) + 1e-6f, -1.f + 1e-6f), 1.f - 1e-6f);
            float sx = fminf(fmaxf(cx + vy * (1.f / wn) + 1e-6f, -1.f + 1e-6f), 1.f - 1e-6f);
            float uy = ((sy + 1.f) * hn - 1.f) * 0.5f;
            float ux = ((sx + 1.f) * wn - 1.f) * 0.5f;
            int iy = min(max((int)rintf(uy), 0), hn - 1);   // round-half-even == jnp.round
            int ix = min(max((int)rintf(ux), 0), wn - 1);
            float oy = -1.f + 1.f / hn + (2.f / hn) * (float)iy;
            float ox = -1.f + 1.f / wn + (2.f / wn) * (float)ix;
            rely[c] = (cy - oy) * hn;
            relx[c] = (cx - ox) * wn;
            area[c] = fabsf(rely[c] * relx[c]) + 1e-9f;
            iyv[c] = iy; ixv[c] = ix;
        }
        const float tot = area[0] + area[1] + area[2] + area[3];
        const float wj = area[3 - j] / tot;   // LIIF area swap 0<->3, 1<->2

        if (j == 0) {  // channels 0..7 (block 0): [rel_y0, rel_x0, ..., rel_y3, rel_x3]
            bf16x8 v;
#pragma unroll
            for (int c = 0; c < 4; c++) { v[2 * c] = (__bf16)rely[c]; v[2 * c + 1] = (__bf16)relx[c]; }
            *(bf16x8*)&Abuf[p][(0 ^ pkey) * 8] = v;
        }
        // channels 8+64j+8*c8 (blocks 1+8j+c8): feat at (iy_j, ix_j) scaled by wj
        const float* fb = feat + ((b * Cn) * hn + iyv[j]) * wn + ixv[j];
#pragma unroll
        for (int c8 = 0; c8 < 8; c8++) {
            bf16x8 v;
#pragma unroll
            for (int cc = 0; cc < 8; cc++)
                v[cc] = (__bf16)(fb[(c8 * 8 + cc) * (hn * wn)] * wj);
            *(bf16x8*)&Abuf[p][((1 + 8 * j + c8) ^ pkey) * 8] = v;
        }
        if (j == 3) {  // blocks 33..35 (k 264..287) zero (rel_cell folded into b1eff)
            bf16x8 z;
#pragma unroll
            for (int cc = 0; cc < 8; cc++) z[cc] = (__bf16)0.f;
            *(bf16x8*)&Abuf[p][(33 ^ pkey) * 8] = z;
            *(bf16x8*)&Abuf[p][(34 ^ pkey) * 8] = z;
            *(bf16x8*)&Abuf[p][(35 ^ pkey) * 8] = z;
        }
    }
    __syncthreads();

    const f32x16 zf16 = (f32x16)(0.f);
    f32x16 c00, c01, c10, c11;
    c00 = zf16; c01 = zf16; c10 = zf16; c11 = zf16;

    // ---------- layer 1: W00[256x288] x G^T, 18 ksteps (K=16), dist-4 ----------
    GS(0,  wP00, wP01); LW(wP00, wP01, wf1, 4);
    GS(1,  wP10, wP11); LW(wP10, wP11, wf1, 5);
    GS(2,  wP20, wP21); LW(wP20, wP21, wf1, 6);
    GS(3,  wP30, wP31); LW(wP30, wP31, wf1, 7);
    GS(4,  wP00, wP01); LW(wP00, wP01, wf1, 8);
    GS(5,  wP10, wP11); LW(wP10, wP11, wf1, 9);
    GS(6,  wP20, wP21); LW(wP20, wP21, wf1, 10);
    GS(7,  wP30, wP31); LW(wP30, wP31, wf1, 11);
    GS(8,  wP00, wP01); LW(wP00, wP01, wf1, 12);
    GS(9,  wP10, wP11); LW(wP10, wP11, wf1, 13);
    GS(10, wP20, wP21); LW(wP20, wP21, wf1, 14);
    GS(11, wP30, wP31); LW(wP30, wP31, wf1, 15);
    GS(12, wP00, wP01); LW(wP00, wP01, wf1, 16);
    GS(13, wP10, wP11); LW(wP10, wP11, wf1, 17);
    GS(14, wP20, wP21); LW(wP20, wP21, wf2, 0);   // L2 k0 -> phase2
    GS(15, wP30, wP31); LW(wP30, wP31, wf2, 1);   // L2 k1 -> phase3
    GS(16, wP00, wP01); LW(wP00, wP01, wf2, 2);   // L2 k2 -> phase0
    GS(17, wP10, wP11); LW(wP10, wP11, wf2, 3);   // L2 k3 -> phase1

    __syncthreads();  // all grid readers done before overwriting Abuf with X
    // epilogue 1: no bias (b00 + rel_cell folded into b1eff); swizzled b64 writes
    EP1(c00, ob0,     lane31);
    EP1(c01, ob0 + 1, lane31);
    EP1(c10, ob0,     32 + lane31);
    EP1(c11, ob0 + 1, 32 + lane31);
    __syncthreads();

    c00 = zf16; c01 = zf16; c10 = zf16; c11 = zf16;

    // ---------- layer 2: W1[256x256] x X, 16 ksteps; kstep j uses phase (j+2)&3 ----------
    GS(0,  wP20, wP21); LW(wP20, wP21, wf2, 4);
    GS(1,  wP30, wP31); LW(wP30, wP31, wf2, 5);
    GS(2,  wP00, wP01); LW(wP00, wP01, wf2, 6);
    GS(3,  wP10, wP11); LW(wP10, wP11, wf2, 7);
    GS(4,  wP20, wP21); LW(wP20, wP21, wf2, 8);
    GS(5,  wP30, wP31); LW(wP30, wP31, wf2, 9);
    GS(6,  wP00, wP01); LW(wP00, wP01, wf2, 10);
    GS(7,  wP10, wP11); LW(wP10, wP11, wf2, 11);
    GS(8,  wP20, wP21); LW(wP20, wP21, wf2, 12);
    GS(9,  wP30, wP31); LW(wP30, wP31, wf2, 13);
    GS(10, wP00, wP01); LW(wP00, wP01, wf2, 14);
    GS(11, wP10, wP11); LW(wP10, wP11, wf2, 15);
    GS(12, wP20, wP21); wP20 = w2f[0 * 64 + lane];   // L3 k0
    GS(13, wP30, wP31); wP30 = w2f[1 * 64 + lane];   // L3 k1
    GS(14, wP00, wP01); wP00 = w2f[2 * 64 + lane];   // L3 k2
    GS(15, wP10, wP11); wP10 = w2f[3 * 64 + lane];   // L3 k3

    __syncthreads();
    // epilogue 2: bias + gelu, swizzled b64 writes
    EP2G(c00, c10, ob0,     0);
    EP2G(c00, c10, ob0,     1);
    EP2G(c00, c10, ob0,     2);
    EP2G(c00, c10, ob0,     3);
    EP2G(c01, c11, ob0 + 1, 0);
    EP2G(c01, c11, ob0 + 1, 1);
    EP2G(c01, c11, ob0 + 1, 2);
    EP2G(c01, c11, ob0 + 1, 3);
    __syncthreads();

    // ---------- layer 3: W2[16x256] x Y (16x16x32), 8 ksteps; wave wv owns px-block wv ----
    f32x4 acc3 = (f32x4){0.f, 0.f, 0.f, 0.f};
    {
        const int row3 = wv * 16 + lane16;
        const int key3 = (row3 >> 3) & 3;
#define YF(k0) (*(const bf16x8*)&Abuf[row3][(((k0) * 4 + quad) ^ key3) * 8])
        acc3 = MF16(wP20, YF(0), acc3); wP20 = w2f[4 * 64 + lane];
        acc3 = MF16(wP30, YF(1), acc3); wP30 = w2f[5 * 64 + lane];
        acc3 = MF16(wP00, YF(2), acc3); wP00 = w2f[6 * 64 + lane];
        acc3 = MF16(wP10, YF(3), acc3); wP10 = w2f[7 * 64 + lane];
        acc3 = MF16(wP20, YF(4), acc3);
        acc3 = MF16(wP30, YF(5), acc3);
        acc3 = MF16(wP00, YF(6), acc3);
        acc3 = MF16(wP10, YF(7), acc3);
#undef YF
    }

    // ---------- epilogue: rows 0..2 (quad 0) hold the 3 output channels ----------
    if (quad == 0) {
        const int pix = wv * 16 + lane16;
        const int X = X0 + pix;
        const float uy = ((cy + 1.f) * hn - 1.f) * 0.5f;
        const float fy = floorf(uy);
        const float wy = uy - fy;
        const int y0i = min(max((int)fy, 0), hn - 1);
        const int y1i = min(max((int)fy + 1, 0), hn - 1);
        const float cx = -1.f + 1.f / Wn + (2.f / Wn) * (float)X;
        const float ux = ((cx + 1.f) * wn - 1.f) * 0.5f;
        const float fx = floorf(ux);
        const float wx = ux - fx;
        const int x0i = min(max((int)fx, 0), wn - 1);
        const int x1i = min(max((int)fx + 1, 0), wn - 1);
        const float w00b = (1.f - wy) * (1.f - wx), w01b = (1.f - wy) * wx;
        const float w10b = wy * (1.f - wx), w11b = wy * wx;
#pragma unroll
        for (int r = 0; r < 3; r++) {
            const float* scb = sc + (b * 3 + r) * (hn * wn);
            const float samp = scb[y0i * wn + x0i] * w00b + scb[y0i * wn + x1i] * w01b
                             + scb[y1i * wn + x0i] * w10b + scb[y1i * wn + x1i] * w11b;
            out[((b * 3 + r) * Hn + Y) * Wn + X] = acc3[r] + b2v[r] + samp;
        }
    }
}

extern "C" void kernel_launch(void* const* d_in, const int* in_sizes, int n_in,
                              void* d_out, int out_size, void* d_ws, size_t ws_size,
                              hipStream_t stream)
{
    const float* feat = (const float*)d_in[0];
    const float* w00  = (const float*)d_in[1];
    const float* b00  = (const float*)d_in[2];
    const float* w1   = (const float*)d_in[3];
    const float* b1   = (const float*)d_in[4];
    const float* w2   = (const float*)d_in[5];
    const float* b2   = (const float*)d_in[6];
    const float* ws1  = (const float*)d_in[7];
    const float* bs1  = (const float*)d_in[8];
    const float* ws2  = (const float*)d_in[9];
    const float* bs2  = (const float*)d_in[10];
    float* out = (float*)d_out;

    __bf16* wb    = (__bf16*)d_ws;
    float* scbuf  = (float*)((char*)d_ws + SC_OFF_BYTES);
    float* b1eff  = (float*)((char*)d_ws + B1EFF_OFF_BYTES);

    prep_all<<<FRAG_BLOCKS + 1 + SC_BLOCKS, 256, 0, stream>>>(
        w00, w1, w2, b00, b1, feat, ws1, bs1, ws2, bs2, wb, b1eff, scbuf);
    liif_main<<<Bn * Hn * (Wn / TM), 256, 0, stream>>>(feat, b1eff, b2, wb, scbuf, out);
}